// Round 12
// baseline (161.805 us; speedup 1.0000x reference)
//
#include <hip/hip_runtime.h>
#include <cmath>

#define DIM      128
#define NELEMS   8388608
#define BAND_INT 12288   // key band >= 7.3e-4 dot units; approx err sigma ~7e-6, Bsq spread ~2e-5
#define NBLOCKS  2048

typedef __attribute__((ext_vector_type(8))) short  short8;
typedef __attribute__((ext_vector_type(4))) float  f32x4;

// ws layout (bytes):
//   0      : float Bsq[1024]        (4096)
//   4096   : int   counts[1024]     (4096)
//   8192   : double sse             (8)
//   12288  : int   done             (4)
//   16384  : ushort Ehi[131072]     (262144)   -> end 278528

__device__ inline unsigned short f2bf(float x) {
    unsigned u = __float_as_uint(x);
    unsigned r = u + 0x7FFFu + ((u >> 16) & 1u);   // RNE; inputs finite
    return (unsigned short)(r >> 16);
}

// async global->LDS, 16B per lane; LDS dest is wave-uniform base + lane*16
__device__ __forceinline__ void gload_lds16(const void* g, void* l) {
    __builtin_amdgcn_global_load_lds(
        (const __attribute__((address_space(1))) void*)g,
        (__attribute__((address_space(3))) void*)l,
        16, 0, 0);
}

// ---- prep: E -> bf16-hi frags [ct64][kt4][lane64][j8] + Bsq (bit-identical tree) + zero ----
__global__ __launch_bounds__(256) void vq_prep_kernel(
        const float* __restrict__ e, unsigned short* __restrict__ Ehi,
        float* __restrict__ Bsq, int* __restrict__ counts, double* __restrict__ sse,
        int* __restrict__ done) {
    const int tid = threadIdx.x;
    {
        const int t  = blockIdx.x * 256 + tid;   // 0..16383
        const int c  = t >> 4;
        const int gs = t & 15;
        const int kt = gs >> 2, qd = gs & 3;
        const int d0 = gs * 8;
        const float4 v0 = *(const float4*)(e + c * DIM + d0);
        const float4 v1 = *(const float4*)(e + c * DIM + d0 + 4);
        float f[8] = {v0.x, v0.y, v0.z, v0.w, v1.x, v1.y, v1.z, v1.w};
        unsigned short h[8];
        #pragma unroll
        for (int j = 0; j < 8; ++j) h[j] = f2bf(f[j]);
        const int ct = c >> 4, n = c & 15;
        uint4 ph;
        ph.x = h[0] | (h[1] << 16); ph.y = h[2] | (h[3] << 16);
        ph.z = h[4] | (h[5] << 16); ph.w = h[6] | (h[7] << 16);
        *(uint4*)&Ehi[(((ct * 4 + kt) * 64 + qd * 16 + n) * 8)] = ph;
    }
    // Bsq: per-row math bit-identical to round-1 rowsq (float4 squares + 32-lane xor tree)
    {
        const int lane = tid & 31;
        #pragma unroll
        for (int r2 = 0; r2 < 2; ++r2) {
            const int row = blockIdx.x * 16 + (tid >> 5) * 2 + r2;
            const float4 xv = *(const float4*)(e + (size_t)row * DIM + lane * 4);
            float s = xv.x * xv.x + xv.y * xv.y + xv.z * xv.z + xv.w * xv.w;
            #pragma unroll
            for (int off = 16; off > 0; off >>= 1) s += __shfl_xor(s, off);
            if (lane == 0) Bsq[row] = s;
        }
    }
    if (blockIdx.x == 0) {
        ((int4*)counts)[tid] = make_int4(0, 0, 0, 0);
        if (tid == 0) { *sse = 0.0; *done = 0; }
    }
}

// ---- main: BARRIER-FREE single-wave scan, depth-2 counted-vmcnt LDS pipeline ----
// 2048 blocks x 64 thr (ONE wave); block = 32 rows x 1024 codes.
// Wave owns 2 row-tiles and scans all 64 cts ascending in 32 tiles of 2 cts (8 KB).
// Producer == consumer == one wave, so the scan needs NO s_barrier at all:
//   STAGE(T0); STAGE(T1); loop { vmcnt(8) [T_it landed, in-order retirement];
//   ds_read + 16 MFMA (lgkmcnt waits before MFMA => reads complete); STAGE(T_it+2)
//   into the buffer just freed }. Every prior variant paid a per-tile SYNCHRONIZED
//   stall (syncthreads vmcnt(0)+s_barrier gating 4-16 waves in lockstep) — the
//   cadence-setter that R9/R10/R11 showed no pipe-level fix could move.
// 8 blocks/CU (LDS 17 KB caps at 9), 2 free-running waves/SIMD.
// Candidates = top-2 over all 64 cts per (row,n): R0 semantics (keys embed distinct
// ct bits -> set is update-order-independent). NO min-waves clause (R2: spills).
// NO per-block __threadfence (R4/R5: L2 wipeout). NO sched_barrier pins (R9).
__global__ __launch_bounds__(64) void vq_main_kernel(
        const float* __restrict__ x, const float* __restrict__ emb,
        const unsigned short* __restrict__ Ehi, const float* __restrict__ Bsq,
        int* __restrict__ counts, double* __restrict__ sse,
        int* __restrict__ done, float* __restrict__ out) {
    // 16 KB region, three sequential lives:
    //   phase 0: A-hi frags [rg2][kt4][lane64][j8] (8 KB)
    //   scan   : B double-buffer, 2 x (2 cts x 4 KB) = 16 KB
    //   phase 2: sc key table, 32 rows x 17 int2 (4352 B)
    __shared__ __align__(16) unsigned short Xs[8192];
    __shared__ float  sAsq[32];
    __shared__ int    sidx[32];
    __shared__ int    sIsLast;

    const int tid  = threadIdx.x;
    const int lane = tid;          // single wave
    const int n    = lane & 15;
    const int quad = lane >> 4;
    const int row0 = blockIdx.x * 32;

    // ---------- phase 0: stage A-hi frags + bit-exact Asq (8 lanes/row xor tree) ----------
    {
        const int rl = tid >> 3, tq = tid & 7;    // 8 rows per pass, 8 threads/row
        const int dbase = tq * 16;
        #pragma unroll
        for (int w = 0; w < 4; ++w) {
            const int r = 8 * w + rl;             // 0..31
            const int rg = r >> 4, m = r & 15;
            const float* xp = x + (size_t)(row0 + r) * DIM + dbase;
            float p[4];
            #pragma unroll
            for (int q = 0; q < 4; ++q) {
                const float4 v = *(const float4*)(xp + 4 * q);
                p[q] = v.x * v.x + v.y * v.y + v.z * v.z + v.w * v.w;
                const int dd = dbase + 4 * q;
                const int kt = dd >> 5, qd = (dd >> 3) & 3, j = dd & 7;
                unsigned short h0 = f2bf(v.x), h1 = f2bf(v.y), h2 = f2bf(v.z), h3 = f2bf(v.w);
                uint2 ph;
                ph.x = h0 | (h1 << 16); ph.y = h2 | (h3 << 16);
                *(uint2*)&Xs[(((rg * 4 + kt) * 64 + qd * 16 + m) * 8) + j] = ph;
            }
            // xor-tree levels identical to prior rounds (8-lane groups) — bit-exact Asq
            #pragma unroll
            for (int q = 0; q < 4; ++q) p[q] += __shfl_xor(p[q], 4);
            #pragma unroll
            for (int q = 0; q < 4; ++q) p[q] += __shfl_xor(p[q], 2);
            #pragma unroll
            for (int q = 0; q < 4; ++q) p[q] += __shfl_xor(p[q], 1);
            const float s = (p[0] + p[2]) + (p[1] + p[3]);
            if (tq == 0) sAsq[r] = s;
        }
    }
    __syncthreads();   // single wave: cheap; orders ds_write -> ds_read (cross-lane)

    short8 Af[2][4];   // row-tiles 0,1 of this block
    #pragma unroll
    for (int rti = 0; rti < 2; ++rti)
        #pragma unroll
        for (int kt = 0; kt < 4; ++kt)
            Af[rti][kt] = *(const short8*)&Xs[(((rti * 4 + kt) * 64 + lane) * 8)];
    __syncthreads();   // frag reads done before Xs becomes the B pipeline buffer

    // ---------- phase 1: barrier-free depth-2 pipeline over 32 tiles x 2 cts ----------
    int K1[8], K2[8];  // [rti*4 + r], top-2 over all 64 cts
    #pragma unroll
    for (int i = 0; i < 8; ++i) { K1[i] = (int)0x80000000; K2[i] = (int)0x80000000; }

    const f32x4 cinit = {1.0f, 1.0f, 1.0f, 1.0f};   // +1.0 bias -> positive, int-monotone keys

    // stage one 8 KB tile (2 cts) = 8 x gload_lds16 (1 KB each) -> 8 vmcnt events
    #define STAGE(BUF, IT)                                                         \
        do {                                                                       \
            const char* _g = (const char*)Ehi + (size_t)(IT) * 8192 + lane * 16;   \
            char*       _l = (char*)Xs + (size_t)(BUF) * 8192 + lane * 16;         \
            _Pragma("unroll")                                                      \
            for (int _k = 0; _k < 8; ++_k)                                         \
                gload_lds16(_g + _k * 1024, _l + _k * 1024);                       \
        } while (0)

    #define COMPUTETILE(BUF, IT)                                                   \
        do {                                                                       \
            _Pragma("unroll")                                                      \
            for (int _c = 0; _c < 2; ++_c) {                                       \
                const int _ct = 2 * (IT) + _c;                                     \
                short8 Bf[4];                                                      \
                _Pragma("unroll")                                                  \
                for (int _kt = 0; _kt < 4; ++_kt)                                  \
                    Bf[_kt] = *(const short8*)&Xs[(size_t)(BUF) * 4096 + _c * 2048 + (_kt * 64 + lane) * 8]; \
                f32x4 _a0 = cinit, _a1 = cinit;                                    \
                _Pragma("unroll")                                                  \
                for (int _kt = 0; _kt < 4; ++_kt) {                                \
                    _a0 = __builtin_amdgcn_mfma_f32_16x16x32_bf16(Af[0][_kt], Bf[_kt], _a0, 0, 0, 0); \
                    _a1 = __builtin_amdgcn_mfma_f32_16x16x32_bf16(Af[1][_kt], Bf[_kt], _a1, 0, 0, 0); \
                }                                                                  \
                _Pragma("unroll")                                                  \
                for (int _r = 0; _r < 4; ++_r) {                                   \
                    int _k0 = (__float_as_int(_a0[_r]) & (int)0xFFFFFFC0) | _ct;   \
                    int _k2n;  /* K2'=med3(K1,K2,k)==max(K2,min(K1,k)), R10-proven */ \
                    asm("v_med3_i32 %0, %1, %2, %3"                                \
                        : "=v"(_k2n) : "v"(K1[_r]), "v"(K2[_r]), "v"(_k0));        \
                    K2[_r] = _k2n;                                                 \
                    K1[_r] = max(K1[_r], _k0);                                     \
                    int _k1 = (__float_as_int(_a1[_r]) & (int)0xFFFFFFC0) | _ct;   \
                    asm("v_med3_i32 %0, %1, %2, %3"                                \
                        : "=v"(_k2n) : "v"(K1[4 + _r]), "v"(K2[4 + _r]), "v"(_k1)); \
                    K2[4 + _r] = _k2n;                                             \
                    K1[4 + _r] = max(K1[4 + _r], _k1);                             \
                }                                                                  \
            }                                                                      \
        } while (0)

    STAGE(0, 0);
    STAGE(1, 1);
    for (int it = 0; it < 31; ++it) {
        // in-order vmcnt retirement: <=8 outstanding => tile `it` fully landed,
        // tile it+1's 8 loads may still be in flight
        asm volatile("s_waitcnt vmcnt(8)" ::: "memory");
        COMPUTETILE(it & 1, it);
        // lgkmcnt waits before the MFMAs above => all ds_reads of buf (it&1) are
        // complete before this STAGE (program order) overwrites it
        if (it < 30) STAGE(it & 1, it + 2);
    }
    asm volatile("s_waitcnt vmcnt(0)" ::: "memory");
    COMPUTETILE(1, 31);
    __syncthreads();   // single wave: orders upcoming sc ds_writes vs pipeline reads
    #undef STAGE
    #undef COMPUTETILE

    // ---------- phase 2: key table (top-2 over all 64 cts per (row,n)) + serial verify ----------
    int2* sc = (int2*)Xs;   // [32 rows][17 entries] (pad +1)
    #pragma unroll
    for (int rti = 0; rti < 2; ++rti)
        #pragma unroll
        for (int r = 0; r < 4; ++r) {
            const int lr = rti * 16 + quad * 4 + r;   // C/D row mapping
            sc[lr * 17 + n] = make_int2(K1[rti * 4 + r], K2[rti * 4 + r]);
        }
    __syncthreads();   // cross-lane ds_write -> ds_read ordering

    float ssum = 0.0f;
    if (tid < 32) {
        const int row  = tid;
        const int rowg = row0 + row;
        const int2* ent = (const int2*)sc + row * 17;
        int mx = (int)0x80000000;
        #pragma unroll
        for (int e2 = 0; e2 < 16; ++e2) mx = max(mx, ent[e2].x);
        const int thr = mx - BAND_INT;
        int ck[8];
        int nc = 0;
        #pragma unroll
        for (int e2 = 0; e2 < 16; ++e2) {
            const int2 kk = ent[e2];
            if (kk.x >= thr && nc < 8) ck[nc++] = ((kk.x & 63) << 4) | e2;
            if (kk.y >= thr && nc < 8) ck[nc++] = ((kk.y & 63) << 4) | e2;
        }
        float bd = INFINITY;
        int   bk = 0x7fffffff;
        const float4* xr = (const float4*)(x + (size_t)rowg * DIM);
        const float   aq = sAsq[row];
        for (int c = 0; c < nc; ++c) {
            const int k = ck[c];
            const float4* er = (const float4*)(emb + (size_t)k * DIM);
            float acc = 0.0f;
            #pragma unroll 4
            for (int dd = 0; dd < 32; ++dd) {   // sequential d order — matches prior rounds / np
                const float4 xv = xr[dd];
                const float4 ev = er[dd];
                acc += xv.x * ev.x;
                acc += xv.y * ev.y;
                acc += xv.z * ev.z;
                acc += xv.w * ev.w;
            }
            const float t    = aq + Bsq[k];
            const float dist = t - 2.0f * acc;
            if (dist < bd || (dist == bd && k < bk)) { bd = dist; bk = k; }
        }
        sidx[row] = bk;
        atomicAdd(&counts[bk], 1);
        ssum = bd;
    }
    #pragma unroll
    for (int off = 32; off > 0; off >>= 1) ssum += __shfl_down(ssum, off);
    if (tid == 0) atomicAdd(sse, (double)ssum);
    __syncthreads();   // sidx visible to all lanes; vmcnt drain completes atomics

    // ---------- phase 3: fused gather + STE epilogue (32 rows x 32 float4) ----------
    #pragma unroll
    for (int i = tid; i < 1024; i += 64) {
        const int row = i >> 5, d4 = i & 31;
        const int k = sidx[row];
        const float4 xv = *((const float4*)(x + (size_t)(row0 + row) * DIM) + d4);
        const float4 qv = *((const float4*)emb + (size_t)k * 32 + d4);
        float4 ov;
        ov.x = xv.x + (qv.x - xv.x);
        ov.y = xv.y + (qv.y - xv.y);
        ov.z = xv.z + (qv.z - xv.z);
        ov.w = xv.w + (qv.w - xv.w);
        *((float4*)out + (size_t)(row0 + row) * 32 + d4) = ov;
    }

    // ---------- phase 4: last-block-done fused finalize (loss + perplexity) ----------
    if (tid == 0) sIsLast = (atomicAdd(done, 1) == NBLOCKS - 1);
    __syncthreads();
    if (sIsLast) {
        __threadfence();   // acquire (single block, once): see all blocks' counts/sse
        double s = 0.0;
        #pragma unroll
        for (int k = tid; k < 1024; k += 64) {
            const float p = (float)counts[k] * (1.0f / 65536.0f);
            s += (double)p * log((double)p + 1e-10);
        }
        #pragma unroll
        for (int off = 32; off > 0; off >>= 1) s += __shfl_down(s, off);
        if (tid == 0) {
            const float m = (float)(*sse * (1.0 / 8388608.0));
            out[NELEMS]     = m + 0.25f * m;
            out[NELEMS + 1] = (float)exp(-s);
        }
    }
}

extern "C" void kernel_launch(void* const* d_in, const int* in_sizes, int n_in,
                              void* d_out, int out_size, void* d_ws, size_t ws_size,
                              hipStream_t stream) {
    const float* x   = (const float*)d_in[0];   // [65536 x 128]
    const float* emb = (const float*)d_in[1];   // [1024 x 128]
    float* out = (float*)d_out;

    char*           ws     = (char*)d_ws;
    float*          Bsq    = (float*)(ws + 0);
    int*            counts = (int*)(ws + 4096);
    double*         sse    = (double*)(ws + 8192);
    int*            done   = (int*)(ws + 12288);
    unsigned short* Ehi    = (unsigned short*)(ws + 16384);

    vq_prep_kernel<<<64, 256, 0, stream>>>(emb, Ehi, Bsq, counts, sse, done);
    vq_main_kernel<<<NBLOCKS, 64, 0, stream>>>(x, emb, Ehi, Bsq, counts, sse, done, out);
}

// Round 14
// 140.140 us; speedup vs baseline: 1.1546x; 1.1546x over previous
//
#include <hip/hip_runtime.h>
#include <cmath>

#define DIM      128
#define NELEMS   8388608
#define BAND_INT 12288   // key band >= 7.3e-4 dot units; approx err sigma ~7e-6, Bsq spread ~2e-5
#define NBLOCKS  1024

typedef __attribute__((ext_vector_type(8))) short  short8;
typedef __attribute__((ext_vector_type(4))) float  f32x4;

// ws layout (bytes):
//   0      : float Bsq[1024]        (4096)
//   4096   : int   counts[1024]     (4096)
//   8192   : double sse             (8)
//   16384  : ushort Ehi[131072]     (262144)   -> end 278528

__device__ inline unsigned short f2bf(float x) {
    unsigned u = __float_as_uint(x);
    unsigned r = u + 0x7FFFu + ((u >> 16) & 1u);   // RNE; inputs finite
    return (unsigned short)(r >> 16);
}

// async global->LDS, 16B per lane; LDS dest is wave-uniform base + lane*16
__device__ __forceinline__ void gload_lds16(const void* g, void* l) {
    __builtin_amdgcn_global_load_lds(
        (const __attribute__((address_space(1))) void*)g,
        (__attribute__((address_space(3))) void*)l,
        16, 0, 0);
}

// ---- prep: E -> bf16-hi frags [ct64][kt4][lane64][j8] + Bsq (bit-identical tree) + zero ----
__global__ __launch_bounds__(256) void vq_prep_kernel(
        const float* __restrict__ e, unsigned short* __restrict__ Ehi,
        float* __restrict__ Bsq, int* __restrict__ counts, double* __restrict__ sse) {
    const int tid = threadIdx.x;
    {
        const int t  = blockIdx.x * 256 + tid;   // 0..16383
        const int c  = t >> 4;
        const int gs = t & 15;
        const int kt = gs >> 2, qd = gs & 3;
        const int d0 = gs * 8;
        const float4 v0 = *(const float4*)(e + c * DIM + d0);
        const float4 v1 = *(const float4*)(e + c * DIM + d0 + 4);
        float f[8] = {v0.x, v0.y, v0.z, v0.w, v1.x, v1.y, v1.z, v1.w};
        unsigned short h[8];
        #pragma unroll
        for (int j = 0; j < 8; ++j) h[j] = f2bf(f[j]);
        const int ct = c >> 4, n = c & 15;
        uint4 ph;
        ph.x = h[0] | (h[1] << 16); ph.y = h[2] | (h[3] << 16);
        ph.z = h[4] | (h[5] << 16); ph.w = h[6] | (h[7] << 16);
        *(uint4*)&Ehi[(((ct * 4 + kt) * 64 + qd * 16 + n) * 8)] = ph;
    }
    // Bsq: per-row math bit-identical to round-1 rowsq (float4 squares + 32-lane xor tree)
    {
        const int lane = tid & 31;
        #pragma unroll
        for (int r2 = 0; r2 < 2; ++r2) {
            const int row = blockIdx.x * 16 + (tid >> 5) * 2 + r2;
            const float4 xv = *(const float4*)(e + (size_t)row * DIM + lane * 4);
            float s = xv.x * xv.x + xv.y * xv.y + xv.z * xv.z + xv.w * xv.w;
            #pragma unroll
            for (int off = 16; off > 0; off >>= 1) s += __shfl_xor(s, off);
            if (lane == 0) Bsq[row] = s;
        }
    }
    if (blockIdx.x == 0) {
        ((int4*)counts)[tid] = make_int4(0, 0, 0, 0);
        if (tid == 0) *sse = 0.0;
    }
}

// ---- main: LDS-staged shared-B bf16 MFMA scan + exact verify + fused STE epilogue ----
// Best-measured scan configuration (R10). 1024 blocks x 256 thr; block = 64 rows x
// 1024 codes; wave w = rows 16w..16w+15, scans all 64 cts ascending (4-ct LDS tiles,
// dbuf). Candidates bit-identical to R0 (absmax 0.001930237).
// NO fused finalize: R13 proved the last-block-done pattern FLAKY — the finalize
// block's PLAIN loads of counts[] occasionally miss other XCDs' device-scope
// atomics despite an acquire __threadfence (per-XCD L2 non-coherence; passed 6
// runs, failed the 7th on post-timing replay check). Loss/perplexity live in a
// separate kernel: the dispatch boundary is an architecturally-guaranteed
// device-scope release/acquire (this structure passed 5/5 rounds, zero flakes).
// Dead-lever table (13 experiments) — do NOT revisit: occupancy 19<->35% (null),
// prefetch depth 2/3 (null/neg), med3 VALU cut (null, kept: free), B-reuse
// 2rt/wave (neg), counted-vmcnt w/ barriers (neg, R9), barrier-free single-wave
// counted-vmcnt (neg, R12), per-block __threadfence (CATASTROPHIC, R4/R5),
// forced min-waves (CATASTROPHIC: VGPR=64 -> 195 MB spills, R2).
__global__ __launch_bounds__(256) void vq_main_kernel(
        const float* __restrict__ x, const float* __restrict__ emb,
        const unsigned short* __restrict__ Ehi, const float* __restrict__ Bsq,
        int* __restrict__ counts, double* __restrict__ sse,
        float* __restrict__ out) {
    // One 32 KB region, three sequential lives:
    //   phase 0: A-hi frags [rg4][kt4][lane64][j8]  (first 16 KB)
    //   scan   : B double-buffer, 2 x (4 cts x 4 KB) = 32 KB
    //   phase 2: sc key table, 64 rows x 17 int2 (8704 B)
    __shared__ __align__(16) unsigned short Xs[16384];
    __shared__ float  sAsq[64];
    __shared__ int    sidx[64];

    const int tid  = threadIdx.x;
    const int wave = tid >> 6;
    const int lane = tid & 63;
    const int n    = lane & 15;
    const int quad = lane >> 4;
    const int row0 = blockIdx.x * 64;

    // ---------- phase 0: stage A-hi frags + bit-exact Asq (prior-round tree) ----------
    {
        const int rl = tid >> 3, tq = tid & 7;    // rl = row 0..31, 8 threads/row
        const int dbase = tq * 16;
        const int rg_lo = rl >> 4, m = rl & 15;
        #pragma unroll
        for (int w = 0; w < 2; ++w) {
            const int r = 32 * w + rl;
            const float* xp = x + (size_t)(row0 + r) * DIM + dbase;
            float p[4];
            #pragma unroll
            for (int q = 0; q < 4; ++q) {
                const float4 v = *(const float4*)(xp + 4 * q);
                p[q] = v.x * v.x + v.y * v.y + v.z * v.z + v.w * v.w;
                const int dd = dbase + 4 * q;
                const int kt = dd >> 5, qd = (dd >> 3) & 3, j = dd & 7;
                unsigned short h0 = f2bf(v.x), h1 = f2bf(v.y), h2 = f2bf(v.z), h3 = f2bf(v.w);
                uint2 ph;
                ph.x = h0 | (h1 << 16); ph.y = h2 | (h3 << 16);
                const int rg = w * 2 + rg_lo;   // == global row >> 4
                *(uint2*)&Xs[(((rg * 4 + kt) * 64 + qd * 16 + m) * 8) + j] = ph;
            }
            // xor-tree levels identical to prior rounds — bit-exact Asq
            #pragma unroll
            for (int q = 0; q < 4; ++q) p[q] += __shfl_xor(p[q], 4);
            #pragma unroll
            for (int q = 0; q < 4; ++q) p[q] += __shfl_xor(p[q], 2);
            #pragma unroll
            for (int q = 0; q < 4; ++q) p[q] += __shfl_xor(p[q], 1);
            const float s = (p[0] + p[2]) + (p[1] + p[3]);
            if (tq == 0) sAsq[r] = s;
        }
    }
    __syncthreads();

    short8 Af[4];        // this wave's single row-tile: rg = wave
    #pragma unroll
    for (int kt = 0; kt < 4; ++kt)
        Af[kt] = *(const short8*)&Xs[(((wave * 4 + kt) * 64 + lane) * 8)];
    __syncthreads();     // all frag reads done before Xs becomes the B staging buffer

    // ---------- phase 1: LDS-staged scan over all 64 cts, 4 cts/tile, dbuf ----------
    int K1[4], K2[4];
    #pragma unroll
    for (int i = 0; i < 4; ++i) { K1[i] = (int)0x80000000; K2[i] = (int)0x80000000; }

    const f32x4 cinit = {1.0f, 1.0f, 1.0f, 1.0f};   // +1.0 bias -> positive, int-monotone keys

    // wave w stages bytes [4096w, 4096w+4096) of each 16 KB tile (4 calls x 1 KB)
    #define STAGE(CUR, IT)                                                                \
        do {                                                                              \
            const char* _g = (const char*)Ehi + (size_t)(IT) * 16384 + wave * 4096 + lane * 16; \
            char*       _l = (char*)Xs + (CUR) * 16384 + wave * 4096;                     \
            gload_lds16(_g,        _l);                                                   \
            gload_lds16(_g + 1024, _l + 1024);                                            \
            gload_lds16(_g + 2048, _l + 2048);                                            \
            gload_lds16(_g + 3072, _l + 3072);                                            \
        } while (0)

    int cur = 0;
    STAGE(0, 0);
    __syncthreads();     // drains staging vmcnt; tile 0 visible to all waves
    for (int it = 0; it < 16; ++it) {
        if (it < 15) STAGE(cur ^ 1, it + 1);   // async prefetch next tile
        // 4 independent MFMA chains (one per ct) — unrolled so LLVM interleaves them
        #pragma unroll
        for (int c = 0; c < 4; ++c) {
            const int ct = 4 * it + c;         // cts ascending 0..63 — same order as R0
            short8 Bf[4];
            #pragma unroll
            for (int kt = 0; kt < 4; ++kt)
                Bf[kt] = *(const short8*)&Xs[(size_t)cur * 8192 + c * 2048 + (kt * 64 + lane) * 8];
            f32x4 a = cinit;
            #pragma unroll
            for (int kt = 0; kt < 4; ++kt)
                a = __builtin_amdgcn_mfma_f32_16x16x32_bf16(Af[kt], Bf[kt], a, 0, 0, 0);
            #pragma unroll
            for (int r = 0; r < 4; ++r) {
                const int k0 = (__float_as_int(a[r]) & (int)0xFFFFFFC0) | ct;
                // top-2 insert: K2' = med3(K1,K2,k0) (== max(K2,min(K1,k0)) given
                // K2<=K1, bit-identical, R10-proven); K1' = max(K1,k0).
                int k2n;
                asm("v_med3_i32 %0, %1, %2, %3"
                    : "=v"(k2n) : "v"(K1[r]), "v"(K2[r]), "v"(k0));
                K2[r] = k2n;
                K1[r] = max(K1[r], k0);
            }
        }
        __syncthreads();   // prefetch landed (vmcnt) + all waves done reading cur (lgkmcnt)
        cur ^= 1;
    }
    #undef STAGE

    // ---------- phase 2: key table (top-2 over all 64 cts per (row,n)) + serial verify ----------
    int2* sc = (int2*)Xs;   // [64 rows][17 entries] (pad +1)
    #pragma unroll
    for (int r = 0; r < 4; ++r) {
        const int lr = wave * 16 + quad * 4 + r;   // C/D row mapping
        sc[lr * 17 + n] = make_int2(K1[r], K2[r]);
    }
    __syncthreads();

    if (tid < 64) {
        const int row  = tid;
        const int rowg = row0 + row;
        const int2* ent = (const int2*)sc + row * 17;
        int mx = (int)0x80000000;
        #pragma unroll
        for (int e2 = 0; e2 < 16; ++e2) mx = max(mx, ent[e2].x);
        const int thr = mx - BAND_INT;
        int ck[8];
        int nc = 0;
        #pragma unroll
        for (int e2 = 0; e2 < 16; ++e2) {
            const int2 kk = ent[e2];
            if (kk.x >= thr && nc < 8) ck[nc++] = ((kk.x & 63) << 4) | e2;
            if (kk.y >= thr && nc < 8) ck[nc++] = ((kk.y & 63) << 4) | e2;
        }
        float bd = INFINITY;
        int   bk = 0x7fffffff;
        const float4* xr = (const float4*)(x + (size_t)rowg * DIM);
        const float   aq = sAsq[row];
        for (int c = 0; c < nc; ++c) {
            const int k = ck[c];
            const float4* er = (const float4*)(emb + (size_t)k * DIM);
            float acc = 0.0f;
            #pragma unroll 4
            for (int dd = 0; dd < 32; ++dd) {   // sequential d order — matches prior rounds / np
                const float4 xv = xr[dd];
                const float4 ev = er[dd];
                acc += xv.x * ev.x;
                acc += xv.y * ev.y;
                acc += xv.z * ev.z;
                acc += xv.w * ev.w;
            }
            const float t    = aq + Bsq[k];
            const float dist = t - 2.0f * acc;
            if (dist < bd || (dist == bd && k < bk)) { bd = dist; bk = k; }
        }
        sidx[row] = bk;
        atomicAdd(&counts[bk], 1);
        float ss = bd;
        #pragma unroll
        for (int off = 32; off > 0; off >>= 1) ss += __shfl_down(ss, off);
        if (tid == 0) atomicAdd(sse, (double)ss);
    }
    __syncthreads();

    // ---------- phase 3: fused gather + STE epilogue (64 rows x 32 float4) ----------
    #pragma unroll
    for (int i = tid; i < 2048; i += 256) {
        const int row = i >> 5, d4 = i & 31;
        const int k = sidx[row];
        const float4 xv = *((const float4*)(x + (size_t)(row0 + row) * DIM) + d4);
        const float4 qv = *((const float4*)emb + (size_t)k * 32 + d4);
        float4 ov;
        ov.x = xv.x + (qv.x - xv.x);
        ov.y = xv.y + (qv.y - xv.y);
        ov.z = xv.z + (qv.z - xv.z);
        ov.w = xv.w + (qv.w - xv.w);
        *((float4*)out + (size_t)(row0 + row) * 32 + d4) = ov;
    }
}

// ---- loss + perplexity (separate dispatch: kernel boundary = guaranteed
//      device-scope release/acquire for counts/sse — no intra-kernel race) ----
__global__ __launch_bounds__(1024) void vq_finalize_kernel(
        const int* __restrict__ counts, const double* __restrict__ sse,
        float* __restrict__ out_tail) {
    __shared__ double red[1024];
    const int t = threadIdx.x;
    const float p = (float)counts[t] * (1.0f / 65536.0f);
    red[t] = (double)p * log((double)p + 1e-10);
    __syncthreads();
    for (int s = 512; s > 0; s >>= 1) {
        if (t < s) red[t] += red[t + s];
        __syncthreads();
    }
    if (t == 0) {
        const float m = (float)(*sse * (1.0 / 8388608.0));
        out_tail[0] = m + 0.25f * m;
        out_tail[1] = (float)exp(-red[0]);
    }
}

extern "C" void kernel_launch(void* const* d_in, const int* in_sizes, int n_in,
                              void* d_out, int out_size, void* d_ws, size_t ws_size,
                              hipStream_t stream) {
    const float* x   = (const float*)d_in[0];   // [65536 x 128]
    const float* emb = (const float*)d_in[1];   // [1024 x 128]
    float* out = (float*)d_out;

    char*           ws     = (char*)d_ws;
    float*          Bsq    = (float*)(ws + 0);
    int*            counts = (int*)(ws + 4096);
    double*         sse    = (double*)(ws + 8192);
    unsigned short* Ehi    = (unsigned short*)(ws + 16384);

    vq_prep_kernel<<<64, 256, 0, stream>>>(emb, Ehi, Bsq, counts, sse);
    vq_main_kernel<<<NBLOCKS, 256, 0, stream>>>(x, emb, Ehi, Bsq, counts, sse, out);
    vq_finalize_kernel<<<1, 1024, 0, stream>>>(counts, sse, out + NELEMS);
}